// Round 3
// baseline (715.126 us; speedup 1.0000x reference)
//
#include <hip/hip_runtime.h>

#define BATCH 262144
#define MARGIN 2e-5f
#define LIST_CAP (1u<<20)

typedef __attribute__((ext_vector_type(8))) short short8;
typedef __attribute__((ext_vector_type(16))) float f32x16;

// ---------------- workspace layout (bytes) ----------------
// 0       : Rt64 f64[128][128]  Rt64[j*128+k] = R[k][j]      (131072)
// 131072  : img  u16: img1h[16384] img1l[16384] img2h[16384] img2l[16384] (131072)
//           img1 frag(kb,jc):  lane l, e -> R[kb*32+(l&31)][jc*16+8*(l>>5)+e]   (mm1 B)
//           img2 frag(jb,kc):  lane l, e -> R[kc*16+8*(l>>5)+e][jb*32+(l&31)]   (mm2 B)
// 262144  : mrot32 f32[128]
// 262656  : counter u32
// 262912  : list u32[LIST_CAP]  (row ids, dups ok)

__device__ __forceinline__ unsigned f2bf(float f) {
  unsigned u = __float_as_uint(f);
  return (u + 0x7FFFu + ((u >> 16) & 1u)) >> 16;   // RTN-even bf16
}
__device__ __forceinline__ unsigned packsplit(float f) {
  unsigned h = f2bf(f);
  float hf = __uint_as_float(h << 16);
  unsigned l = f2bf(f - hf);
  return (h << 16) | l;      // hi16 = bf16 high part, lo16 = bf16 low part
}

// =======================================================================
// K_pre: register-resident Gauss-Jordan inversion of M = I + A (no
// pivoting; cond ~1.5). R = 2*(I+A)^-1 - I. Emits Rt64 (f64), bf16
// hi/lo fragment images for mm1/mm2 B-operands, and mrot = mean@R^T.
// =======================================================================
__global__ __launch_bounds__(1024)
void kpre(const float* __restrict__ skew, const float* __restrict__ mean,
          double* __restrict__ Rt64, unsigned short* __restrict__ img,
          float* __restrict__ mrot32)
{
  __shared__ double colk[128];
  __shared__ double pivrow[128];
  __shared__ double mred[128][8];
  const int tid = threadIdx.x;
  const int i = tid >> 3;
  const int s = tid & 7;

  double M[16];
  #pragma unroll
  for (int e = 0; e < 16; ++e) {
    int j = s + 8*e;
    double v;
    if (i == j)      v = 1.0;
    else if (i < j)  v =  (double)skew[i*127 - (i*(i-1))/2 + (j - i - 1)];
    else             v = -(double)skew[j*127 - (j*(j-1))/2 + (i - j - 1)];
    M[e] = v;
  }
  __syncthreads();

  for (int k = 0; k < 128; ++k) {
    if (s == (k & 7)) colk[i] = M[k >> 3];
    __syncthreads();
    if (i == k) {
      double rec = 1.0 / colk[k];
      #pragma unroll
      for (int e = 0; e < 16; ++e) {
        int j = s + 8*e;
        double v = (j == k) ? 1.0 : M[e];
        v *= rec;
        M[e] = v;
        pivrow[j] = v;
      }
    }
    __syncthreads();
    if (i != k) {
      double f = colk[i];
      #pragma unroll
      for (int e = 0; e < 16; ++e) {
        int j = s + 8*e;
        double v = (j == k) ? 0.0 : M[e];
        M[e] = fma(-f, pivrow[j], v);
      }
    }
    __syncthreads();
  }

  double mpart = 0.0;
  #pragma unroll
  for (int e = 0; e < 16; ++e) {
    int j = s + 8*e;
    double v = 2.0 * M[e] - ((i == j) ? 1.0 : 0.0);    // R[i][j]
    Rt64[j*128 + i] = v;
    float r32 = (float)v;
    unsigned h = f2bf(r32);
    unsigned l = f2bf(r32 - __uint_as_float(h << 16));
    // img1 (mm1 B): n=i (k-dim), K=j
    int off1 = (((i>>5)*8 + (j>>4))*64 + ((((j>>3)&1)<<5) | (i&31)))*8 + (j&7);
    img[off1]          = (unsigned short)h;
    img[16384 + off1]  = (unsigned short)l;
    // img2 (mm2 B): n=j (out col), K=i (quant dim)
    int off2 = (((j>>5)*8 + (i>>4))*64 + ((((i>>3)&1)<<5) | (j&31)))*8 + (i&7);
    img[32768 + off2]  = (unsigned short)h;
    img[49152 + off2]  = (unsigned short)l;
    mpart = fma((double)mean[j], v, mpart);
  }
  mred[i][s] = mpart;
  __syncthreads();
  if (s == 0) {
    double t = 0.0;
    #pragma unroll
    for (int e = 0; e < 8; ++e) t += mred[i][e];
    mrot32[i] = (float)t;
  }
}

#define UNPACK_FRAG(ap, AH, AL)                                         \
  {                                                                     \
    uint2 u0 = *(const uint2*)((ap));                                   \
    uint2 u1 = *(const uint2*)((ap)+2);                                 \
    uint2 u2 = *(const uint2*)((ap)+4);                                 \
    uint2 u3 = *(const uint2*)((ap)+6);                                 \
    AH.w_[0] = (u0.y & 0xFFFF0000u) | (u0.x >> 16);                     \
    AL.w_[0] = (u0.y << 16) | (u0.x & 0xFFFFu);                         \
    AH.w_[1] = (u1.y & 0xFFFF0000u) | (u1.x >> 16);                     \
    AL.w_[1] = (u1.y << 16) | (u1.x & 0xFFFFu);                         \
    AH.w_[2] = (u2.y & 0xFFFF0000u) | (u2.x >> 16);                     \
    AL.w_[2] = (u2.y << 16) | (u2.x & 0xFFFFu);                         \
    AH.w_[3] = (u3.y & 0xFFFF0000u) | (u3.x >> 16);                     \
    AL.w_[3] = (u3.y << 16) | (u3.x & 0xFFFFu);                         \
  }

// =======================================================================
// K_main: fused rotate+quantize+reconstruct. 256 blocks x 256 thr,
// 32-row chunks, MFMA 32x32x16 bf16 3-term split for both matmuls.
// LDS: [0,131072) B-frag images; [131072,147712) xc/q shared u32[32][130];
// [147712..) norms/invs.
// =======================================================================
__global__ __launch_bounds__(256)
void kmain(const float* __restrict__ x, const float* __restrict__ mean,
           const float* __restrict__ cent, const float* __restrict__ mrot32,
           const float* __restrict__ imgf, float* __restrict__ out,
           unsigned int* __restrict__ counter, unsigned int* __restrict__ list)
{
  extern __shared__ char smem[];
  unsigned short* i1h = (unsigned short*)smem;
  unsigned short* i1l = (unsigned short*)(smem + 32768);
  unsigned short* i2h = (unsigned short*)(smem + 65536);
  unsigned short* i2l = (unsigned short*)(smem + 98304);
  unsigned* xcq = (unsigned*)(smem + 131072);    // [32][130]
  float* norms = (float*)(smem + 147712);
  float* invs  = (float*)(smem + 147840);

  const int tid = threadIdx.x, lane = tid & 63, w = tid >> 6;
  const int al31 = lane & 31, ah = lane >> 5;

  {  // stage fragment images (131072 B) once
    const float4* src = (const float4*)imgf;
    float4* dst = (float4*)smem;
    #pragma unroll
    for (int it = 0; it < 32; ++it) dst[it*256 + tid] = src[it*256 + tid];
  }

  const float c0 = cent[0], c1 = cent[1], c2 = cent[2], c3 = cent[3];
  const float c4 = cent[4], c5 = cent[5], c6 = cent[6], c7 = cent[7];
  const float mid0 = 0.5f*(c0+c1), mid1 = 0.5f*(c1+c2), mid2 = 0.5f*(c2+c3),
              mid3 = 0.5f*(c3+c4), mid4 = 0.5f*(c4+c5), mid5 = 0.5f*(c5+c6),
              mid6 = 0.5f*(c6+c7);
  const unsigned qt0 = packsplit(c0), qt1 = packsplit(c1), qt2 = packsplit(c2),
                 qt3 = packsplit(c3), qt4 = packsplit(c4), qt5 = packsplit(c5),
                 qt6 = packsplit(c6), qt7 = packsplit(c7);

  const float2 mean2 = *(const float2*)(mean + 2*lane);
  const float mrotv = mrot32[w*32 + al31];
  const float meanv = mean[w*32 + al31];

  const int blk0 = blockIdx.x * 1024;

  float2 xva[8], xvb[8];
  #pragma unroll
  for (int rr = 0; rr < 8; ++rr)
    xva[rr] = *(const float2*)(x + (size_t)(blk0 + w*8 + rr)*128 + 2*lane);
  __syncthreads();   // images staged

  auto proc = [&](float2 (&cur)[8], float2 (&nxt)[8], int i) {
    const int chb = blk0 + i*32;
    // ---- prefetch next chunk (consumed next call) ----
    const int nbase = min(chb + 32, BATCH - 32);
    #pragma unroll
    for (int rr = 0; rr < 8; ++rr)
      nxt[rr] = *(const float2*)(x + (size_t)(nbase + w*8 + rr)*128 + 2*lane);

    // ---- stage: center, norm, split-bf16 pack -> LDS ----
    #pragma unroll
    for (int rr = 0; rr < 8; ++rr) {
      float a = cur[rr].x - mean2.x;
      float b = cur[rr].y - mean2.y;
      float sq = fmaf(a, a, b*b);
      sq += __shfl_xor(sq, 1);  sq += __shfl_xor(sq, 2);  sq += __shfl_xor(sq, 4);
      sq += __shfl_xor(sq, 8);  sq += __shfl_xor(sq, 16); sq += __shfl_xor(sq, 32);
      uint2 pw; pw.x = packsplit(a); pw.y = packsplit(b);
      *(uint2*)(xcq + (w*8 + rr)*130 + 2*lane) = pw;
      if (lane == 0) {
        float n = fmaxf(sqrtf(sq), 1e-8f);
        norms[w*8 + rr] = n;
        invs [w*8 + rr] = 1.0f / n;
      }
    }
    __syncthreads();                       // XC image complete

    // ---- mm1: x_rot^pre = XC @ R^T, tile kb = w ----
    f32x16 acc1;
    #pragma unroll
    for (int g = 0; g < 16; ++g) acc1[g] = 0.0f;
    #pragma unroll
    for (int jc = 0; jc < 8; ++jc) {
      const unsigned* ap = xcq + al31*130 + jc*16 + ah*8;
      union { unsigned w_[4]; short8 s; } Ah, Al;
      UNPACK_FRAG(ap, Ah, Al);
      short8 bh = *(const short8*)(i1h + ((w*8 + jc)*64 + lane)*8);
      short8 bl = *(const short8*)(i1l + ((w*8 + jc)*64 + lane)*8);
      acc1 = __builtin_amdgcn_mfma_f32_32x32x16_bf16(Ah.s, bh, acc1, 0, 0, 0);
      acc1 = __builtin_amdgcn_mfma_f32_32x32x16_bf16(Al.s, bh, acc1, 0, 0, 0);
      acc1 = __builtin_amdgcn_mfma_f32_32x32x16_bf16(Ah.s, bl, acc1, 0, 0, 0);
    }

    // ---- quantize (regs) ----
    unsigned qp[16];
    bool fl[16];
    #pragma unroll
    for (int g = 0; g < 16; ++g) {
      int r = (g&3) + 8*(g>>2) + 4*ah;
      float xr = (acc1[g] - mrotv) * invs[r];
      unsigned q = qt0;
      q = (xr > mid0) ? qt1 : q;  q = (xr > mid1) ? qt2 : q;
      q = (xr > mid2) ? qt3 : q;  q = (xr > mid3) ? qt4 : q;
      q = (xr > mid4) ? qt5 : q;  q = (xr > mid5) ? qt6 : q;
      q = (xr > mid6) ? qt7 : q;
      float dm = fabsf(xr - mid0);
      dm = fminf(dm, fabsf(xr - mid1)); dm = fminf(dm, fabsf(xr - mid2));
      dm = fminf(dm, fabsf(xr - mid3)); dm = fminf(dm, fabsf(xr - mid4));
      dm = fminf(dm, fabsf(xr - mid5)); dm = fminf(dm, fabsf(xr - mid6));
      qp[g] = q;
      fl[g] = dm < MARGIN;
    }
    __syncthreads();                       // all mm1 XC reads done

    // ---- write Q image (same buffer) + patch-list append ----
    #pragma unroll
    for (int g = 0; g < 16; ++g) {
      int r = (g&3) + 8*(g>>2) + 4*ah;
      xcq[r*130 + w*32 + al31] = qp[g];
      unsigned long long b = __ballot(fl[g]);
      if (b) {
        unsigned base = 0;
        if (lane == 0) base = atomicAdd(counter, (unsigned)__popcll(b));
        base = (unsigned)__shfl((int)base, 0);
        if (fl[g]) {
          unsigned p = base + (unsigned)__popcll(b & ((1ull << lane) - 1ull));
          if (p < LIST_CAP) list[p] = (unsigned)(chb + r);
        }
      }
    }
    __syncthreads();                       // Q image complete

    // ---- mm2: out = Q @ R, tile jb = w ----
    f32x16 acc2;
    #pragma unroll
    for (int g = 0; g < 16; ++g) acc2[g] = 0.0f;
    #pragma unroll
    for (int kc = 0; kc < 8; ++kc) {
      const unsigned* ap = xcq + al31*130 + kc*16 + ah*8;
      union { unsigned w_[4]; short8 s; } Ah, Al;
      UNPACK_FRAG(ap, Ah, Al);
      short8 bh = *(const short8*)(i2h + ((w*8 + kc)*64 + lane)*8);
      short8 bl = *(const short8*)(i2l + ((w*8 + kc)*64 + lane)*8);
      acc2 = __builtin_amdgcn_mfma_f32_32x32x16_bf16(Ah.s, bh, acc2, 0, 0, 0);
      acc2 = __builtin_amdgcn_mfma_f32_32x32x16_bf16(Al.s, bh, acc2, 0, 0, 0);
      acc2 = __builtin_amdgcn_mfma_f32_32x32x16_bf16(Ah.s, bl, acc2, 0, 0, 0);
    }

    // ---- epilogue: scale + recenter + store ----
    #pragma unroll
    for (int g = 0; g < 16; ++g) {
      int r = (g&3) + 8*(g>>2) + 4*ah;
      float o = fmaf(acc2[g], norms[r], meanv);
      out[(size_t)(chb + r)*128 + w*32 + al31] = o;
    }
    __syncthreads();                       // mm2 Q reads done before next stage
  };

  for (int i = 0; i < 32; i += 2) {
    proc(xva, xvb, i);
    proc(xvb, xva, i + 1);
  }
}

// =======================================================================
// K_fix: exact f64 recompute of rows whose some element was within
// MARGIN of a quantization midpoint. One wave per row; overwrites out.
// =======================================================================
__global__ __launch_bounds__(256)
void kfix(const float* __restrict__ x, const float* __restrict__ mean,
          const float* __restrict__ cent, const double* __restrict__ Rt64,
          float* __restrict__ out,
          const unsigned int* __restrict__ counter,
          const unsigned int* __restrict__ list)
{
  __shared__ double xs[4][128];
  __shared__ double qs[4][128];
  const int tid = threadIdx.x, lane = tid & 63, w = tid >> 6;

  unsigned cnt = *counter;
  if (cnt > LIST_CAP) cnt = LIST_CAP;

  const double cc0 = (double)cent[0], cc1 = (double)cent[1], cc2 = (double)cent[2],
               cc3 = (double)cent[3], cc4 = (double)cent[4], cc5 = (double)cent[5],
               cc6 = (double)cent[6], cc7 = (double)cent[7];
  const double m0 = 0.5*(cc0+cc1), m1 = 0.5*(cc1+cc2), m2 = 0.5*(cc2+cc3),
               m3 = 0.5*(cc3+cc4), m4 = 0.5*(cc4+cc5), m5 = 0.5*(cc5+cc6),
               m6 = 0.5*(cc6+cc7);

  const unsigned gw = blockIdx.x*4 + w, stride = gridDim.x*4;
  for (unsigned e = gw; e < cnt; e += stride) {
    const int row = (int)list[e];
    const float* xr = x + (size_t)row*128;
    const int j0 = 2*lane;

    double a = (double)xr[j0]   - (double)mean[j0];
    double b = (double)xr[j0+1] - (double)mean[j0+1];
    double s = a*a + b*b;
    s += __shfl_xor(s, 1);  s += __shfl_xor(s, 2);  s += __shfl_xor(s, 4);
    s += __shfl_xor(s, 8);  s += __shfl_xor(s, 16); s += __shfl_xor(s, 32);
    double n = sqrt(s);
    if (n < 1e-8) n = 1e-8;
    double inv = 1.0 / n;
    xs[w][j0]   = a * inv;
    xs[w][j0+1] = b * inv;
    asm volatile("s_waitcnt lgkmcnt(0)" ::: "memory");

    double acc0 = 0.0, acc1 = 0.0;
    for (int j = 0; j < 128; ++j) {
      double xj = xs[w][j];
      acc0 = fma(xj, Rt64[j*128 + j0],     acc0);
      acc1 = fma(xj, Rt64[j*128 + j0 + 1], acc1);
    }
    double q0 = cc0;
    q0 = (acc0 > m0) ? cc1 : q0;  q0 = (acc0 > m1) ? cc2 : q0;
    q0 = (acc0 > m2) ? cc3 : q0;  q0 = (acc0 > m3) ? cc4 : q0;
    q0 = (acc0 > m4) ? cc5 : q0;  q0 = (acc0 > m5) ? cc6 : q0;
    q0 = (acc0 > m6) ? cc7 : q0;
    double q1 = cc0;
    q1 = (acc1 > m0) ? cc1 : q1;  q1 = (acc1 > m1) ? cc2 : q1;
    q1 = (acc1 > m2) ? cc3 : q1;  q1 = (acc1 > m3) ? cc4 : q1;
    q1 = (acc1 > m4) ? cc5 : q1;  q1 = (acc1 > m5) ? cc6 : q1;
    q1 = (acc1 > m6) ? cc7 : q1;
    qs[w][j0]   = q0;
    qs[w][j0+1] = q1;
    asm volatile("s_waitcnt lgkmcnt(0)" ::: "memory");

    double o0 = 0.0, o1 = 0.0;
    for (int k = 0; k < 128; ++k) {
      double qk = qs[w][k];
      o0 = fma(qk, Rt64[j0*128 + k],       o0);
      o1 = fma(qk, Rt64[(j0+1)*128 + k],   o1);
    }
    out[(size_t)row*128 + j0]   = (float)fma(o0, n, (double)mean[j0]);
    out[(size_t)row*128 + j0+1] = (float)fma(o1, n, (double)mean[j0+1]);
  }
}

// =======================================================================
extern "C" void kernel_launch(void* const* d_in, const int* in_sizes, int n_in,
                              void* d_out, int out_size, void* d_ws, size_t ws_size,
                              hipStream_t stream)
{
  (void)in_sizes; (void)n_in; (void)out_size; (void)ws_size;
  const float* x    = (const float*)d_in[0];
  const float* skew = (const float*)d_in[1];
  const float* cent = (const float*)d_in[2];
  const float* mean = (const float*)d_in[3];
  float* out = (float*)d_out;

  char* ws = (char*)d_ws;
  double*         Rt64   = (double*)(ws);
  unsigned short* img    = (unsigned short*)(ws + 131072);
  const float*    imgf   = (const float*)(ws + 131072);
  float*          mrot32 = (float*)(ws + 262144);
  unsigned int*   cntr   = (unsigned int*)(ws + 262656);
  unsigned int*   list   = (unsigned int*)(ws + 262912);

  hipMemsetAsync(cntr, 0, 4, stream);
  kpre <<<dim3(1),   dim3(1024), 0,      stream>>>(skew, mean, Rt64, img, mrot32);
  kmain<<<dim3(256), dim3(256),  147968, stream>>>(x, mean, cent, mrot32, imgf, out, cntr, list);
  kfix <<<dim3(192), dim3(256),  0,      stream>>>(x, mean, cent, Rt64, out, cntr, list);
}

// Round 4
// 579.103 us; speedup vs baseline: 1.2349x; 1.2349x over previous
//
#include <hip/hip_runtime.h>

#define BATCH 262144
#define MARGIN 2e-5f
#define LIST_CAP (1u<<20)

typedef __attribute__((ext_vector_type(8))) short short8;
typedef __attribute__((ext_vector_type(16))) float f32x16;

// ---------------- workspace layout (bytes) ----------------
// 0       : Rt64 f64[128][128]  Rt64[j*128+k] = R[k][j]      (131072)
// 131072  : img  u16: i1h[16384] i1l[16384] i2h[16384] i2l[16384] (131072)
//           img1 frag(kb,jc): lane l,e -> R[kb*32+(l&31)][jc*16+8*(l>>5)+e]  (mm1 B)
//           img2 frag(jb,kc): lane l,e -> R[kc*16+8*(l>>5)+e][jb*32+(l&31)]  (mm2 B)
// 262144  : counter u32
// 262912  : list u32[LIST_CAP]  (row ids, dups ok)

__device__ __forceinline__ unsigned f2bf(float f) {
  unsigned u = __float_as_uint(f);
  return (u + 0x7FFFu + ((u >> 16) & 1u)) >> 16;   // RTN-even bf16
}
__device__ __forceinline__ unsigned packsplit(float f) {
  unsigned h = f2bf(f);
  float hf = __uint_as_float(h << 16);
  unsigned l = f2bf(f - hf);
  return (h << 16) | l;
}

// =======================================================================
// K_pre: register-resident Gauss-Jordan inversion of M = I + A (no
// pivoting; cond ~1.5). R = 2*(I+A)^-1 - I. Emits Rt64 (f64) and bf16
// hi/lo fragment images for mm1/mm2 B-operands.
// =======================================================================
__global__ __launch_bounds__(1024)
void kpre(const float* __restrict__ skew, double* __restrict__ Rt64,
          unsigned short* __restrict__ img)
{
  __shared__ double colk[128];
  __shared__ double pivrow[128];
  const int tid = threadIdx.x;
  const int i = tid >> 3;
  const int s = tid & 7;

  double M[16];
  #pragma unroll
  for (int e = 0; e < 16; ++e) {
    int j = s + 8*e;
    double v;
    if (i == j)      v = 1.0;
    else if (i < j)  v =  (double)skew[i*127 - (i*(i-1))/2 + (j - i - 1)];
    else             v = -(double)skew[j*127 - (j*(j-1))/2 + (i - j - 1)];
    M[e] = v;
  }
  __syncthreads();

  for (int k = 0; k < 128; ++k) {
    if (s == (k & 7)) colk[i] = M[k >> 3];
    __syncthreads();
    if (i == k) {
      double rec = 1.0 / colk[k];
      #pragma unroll
      for (int e = 0; e < 16; ++e) {
        int j = s + 8*e;
        double v = (j == k) ? 1.0 : M[e];
        v *= rec;
        M[e] = v;
        pivrow[j] = v;
      }
    }
    __syncthreads();
    if (i != k) {
      double f = colk[i];
      #pragma unroll
      for (int e = 0; e < 16; ++e) {
        int j = s + 8*e;
        double v = (j == k) ? 0.0 : M[e];
        M[e] = fma(-f, pivrow[j], v);
      }
    }
    __syncthreads();
  }

  #pragma unroll
  for (int e = 0; e < 16; ++e) {
    int j = s + 8*e;
    double v = 2.0 * M[e] - ((i == j) ? 1.0 : 0.0);    // R[i][j]
    Rt64[j*128 + i] = v;
    float r32 = (float)v;
    unsigned h = f2bf(r32);
    unsigned l = f2bf(r32 - __uint_as_float(h << 16));
    int off1 = (((i>>5)*8 + (j>>4))*64 + ((((j>>3)&1)<<5) | (i&31)))*8 + (j&7);
    img[off1]          = (unsigned short)h;
    img[16384 + off1]  = (unsigned short)l;
    int off2 = (((j>>5)*8 + (i>>4))*64 + ((((i>>3)&1)<<5) | (j&31)))*8 + (i&7);
    img[32768 + off2]  = (unsigned short)h;
    img[49152 + off2]  = (unsigned short)l;
  }
}

// =======================================================================
// K_main: fused rotate+quantize+reconstruct. 1024 blocks x 256 thr,
// 8 chunks x 32 rows per block. LDS holds ONLY the X/Q hi/lo image
// (XOR-swizzled) + norms; R B-fragments stream from global (L2-resident).
// =======================================================================
#define MM3(ACC, XH, XL, BH, BL)                                        \
  ACC = __builtin_amdgcn_mfma_f32_32x32x16_bf16(XH, BH, ACC, 0, 0, 0);  \
  ACC = __builtin_amdgcn_mfma_f32_32x32x16_bf16(XL, BH, ACC, 0, 0, 0);  \
  ACC = __builtin_amdgcn_mfma_f32_32x32x16_bf16(XH, BL, ACC, 0, 0, 0);

#define FRAGS(JC, XH, XL, BH, BL, GH, GL)                               \
  {                                                                     \
    unsigned fb = ((unsigned)(al*256 + (JC)*32 + ah*16)) ^ (swzA);      \
    XH = *(const short8*)((const char*)Xh + fb);                        \
    XL = *(const short8*)((const char*)Xl + fb);                        \
    BH = *(const short8*)((GH) + (size_t)((w*8 + (JC))*64 + lane)*8);   \
    BL = *(const short8*)((GL) + (size_t)((w*8 + (JC))*64 + lane)*8);   \
  }

__global__ __launch_bounds__(256, 3)
void kmain(const float* __restrict__ x, const float* __restrict__ mean,
           const float* __restrict__ cent, const unsigned short* __restrict__ img,
           float* __restrict__ out,
           unsigned int* __restrict__ counter, unsigned int* __restrict__ list)
{
  __shared__ __align__(16) unsigned short Xh[32*128];   // 8 KB (swizzled)
  __shared__ __align__(16) unsigned short Xl[32*128];   // 8 KB (swizzled)
  __shared__ float norms[32];
  __shared__ float invs[32];

  const int tid = threadIdx.x, lane = tid & 63, w = tid >> 6;
  const int al = lane & 31, ah = lane >> 5;
  const unsigned swzA = ((unsigned)(al & 7)) << 4;

  const unsigned short* i1h = img;
  const unsigned short* i1l = img + 16384;
  const unsigned short* i2h = img + 32768;
  const unsigned short* i2l = img + 49152;

  const float c0 = cent[0], c1 = cent[1], c2 = cent[2], c3 = cent[3];
  const float c4 = cent[4], c5 = cent[5], c6 = cent[6], c7 = cent[7];
  const float mid0 = 0.5f*(c0+c1), mid1 = 0.5f*(c1+c2), mid2 = 0.5f*(c2+c3),
              mid3 = 0.5f*(c3+c4), mid4 = 0.5f*(c4+c5), mid5 = 0.5f*(c5+c6),
              mid6 = 0.5f*(c6+c7);
  const unsigned qt0 = packsplit(c0), qt1 = packsplit(c1), qt2 = packsplit(c2),
                 qt3 = packsplit(c3), qt4 = packsplit(c4), qt5 = packsplit(c5),
                 qt6 = packsplit(c6), qt7 = packsplit(c7);

  const float2 mean2 = *(const float2*)(mean + 2*lane);
  const float meanv = mean[w*32 + al];

  const int row0 = blockIdx.x * 256;

  for (int ch = 0; ch < 8; ++ch) {
    const int chb = row0 + ch*32;

    // ---- stage: center, norm, split-bf16, swizzled LDS write ----
    #pragma unroll
    for (int rr = 0; rr < 8; ++rr) {
      const int r = w*8 + rr;
      float2 xv = *(const float2*)(x + (size_t)(chb + r)*128 + 2*lane);
      float a = xv.x - mean2.x;
      float b = xv.y - mean2.y;
      float sq = fmaf(a, a, b*b);
      sq += __shfl_xor(sq, 1);  sq += __shfl_xor(sq, 2);  sq += __shfl_xor(sq, 4);
      sq += __shfl_xor(sq, 8);  sq += __shfl_xor(sq, 16); sq += __shfl_xor(sq, 32);
      unsigned pa = packsplit(a), pb = packsplit(b);
      unsigned off = ((unsigned)(r*256 + 4*lane)) ^ (((unsigned)(r & 7)) << 4);
      *(unsigned*)((char*)Xh + off) = (pb & 0xFFFF0000u) | (pa >> 16);
      *(unsigned*)((char*)Xl + off) = (pb << 16) | (pa & 0xFFFFu);
      if (lane == 0) {
        float n = fmaxf(sqrtf(sq), 1e-8f);
        norms[r] = n;
        invs[r]  = 1.0f / n;
      }
    }
    __syncthreads();

    // ---- mm1: rows @ R^T (tile kb = w), 2 independent acc chains ----
    f32x16 accA, accB;
    #pragma unroll
    for (int g = 0; g < 16; ++g) { accA[g] = 0.0f; accB[g] = 0.0f; }
    {
      short8 xh, xl, bh, bl;
      FRAGS(0, xh, xl, bh, bl, i1h, i1l);  MM3(accA, xh, xl, bh, bl);
      FRAGS(1, xh, xl, bh, bl, i1h, i1l);  MM3(accB, xh, xl, bh, bl);
      FRAGS(2, xh, xl, bh, bl, i1h, i1l);  MM3(accA, xh, xl, bh, bl);
      FRAGS(3, xh, xl, bh, bl, i1h, i1l);  MM3(accB, xh, xl, bh, bl);
      FRAGS(4, xh, xl, bh, bl, i1h, i1l);  MM3(accA, xh, xl, bh, bl);
      FRAGS(5, xh, xl, bh, bl, i1h, i1l);  MM3(accB, xh, xl, bh, bl);
      FRAGS(6, xh, xl, bh, bl, i1h, i1l);  MM3(accA, xh, xl, bh, bl);
      FRAGS(7, xh, xl, bh, bl, i1h, i1l);  MM3(accB, xh, xl, bh, bl);
    }
    #pragma unroll
    for (int g = 0; g < 16; ++g) accA[g] += accB[g];

    // ---- quantize (regs) ----
    unsigned qp[16];
    unsigned flags = 0;
    #pragma unroll
    for (int g = 0; g < 16; ++g) {
      const int r = (g & 3) + 8*(g >> 2) + 4*ah;
      float xr = accA[g] * invs[r];
      unsigned q = qt0;
      q = (xr > mid0) ? qt1 : q;  q = (xr > mid1) ? qt2 : q;
      q = (xr > mid2) ? qt3 : q;  q = (xr > mid3) ? qt4 : q;
      q = (xr > mid4) ? qt5 : q;  q = (xr > mid5) ? qt6 : q;
      q = (xr > mid6) ? qt7 : q;
      float dm = fabsf(xr - mid0);
      dm = fminf(dm, fabsf(xr - mid1)); dm = fminf(dm, fabsf(xr - mid2));
      dm = fminf(dm, fabsf(xr - mid3)); dm = fminf(dm, fabsf(xr - mid4));
      dm = fminf(dm, fabsf(xr - mid5)); dm = fminf(dm, fabsf(xr - mid6));
      qp[g] = q;
      flags |= (dm < MARGIN) ? (1u << g) : 0u;
    }
    __syncthreads();              // all mm1 X reads done before overwrite

    // ---- write Q image (overwrites X image) + patch-list append ----
    #pragma unroll
    for (int g = 0; g < 16; ++g) {
      const int rq = (g & 3) + 8*(g >> 2) + 4*ah;
      unsigned off = ((unsigned)(rq*256 + (w*32 + al)*2)) ^ (((unsigned)(rq & 7)) << 4);
      *(unsigned short*)((char*)Xh + off) = (unsigned short)(qp[g] >> 16);
      *(unsigned short*)((char*)Xl + off) = (unsigned short)(qp[g] & 0xFFFFu);
      unsigned long long b = __ballot((flags >> g) & 1u);
      if (b) {
        unsigned base = 0;
        if (lane == 0) base = atomicAdd(counter, (unsigned)__popcll(b));
        base = (unsigned)__shfl((int)base, 0);
        if ((flags >> g) & 1u) {
          unsigned p = base + (unsigned)__popcll(b & ((1ull << lane) - 1ull));
          if (p < LIST_CAP) list[p] = (unsigned)(chb + rq);
        }
      }
    }
    __syncthreads();              // Q image complete

    // ---- mm2: Q @ R (tile jb = w) ----
    f32x16 acc2, acc3;
    #pragma unroll
    for (int g = 0; g < 16; ++g) { acc2[g] = 0.0f; acc3[g] = 0.0f; }
    {
      short8 xh, xl, bh, bl;
      FRAGS(0, xh, xl, bh, bl, i2h, i2l);  MM3(acc2, xh, xl, bh, bl);
      FRAGS(1, xh, xl, bh, bl, i2h, i2l);  MM3(acc3, xh, xl, bh, bl);
      FRAGS(2, xh, xl, bh, bl, i2h, i2l);  MM3(acc2, xh, xl, bh, bl);
      FRAGS(3, xh, xl, bh, bl, i2h, i2l);  MM3(acc3, xh, xl, bh, bl);
      FRAGS(4, xh, xl, bh, bl, i2h, i2l);  MM3(acc2, xh, xl, bh, bl);
      FRAGS(5, xh, xl, bh, bl, i2h, i2l);  MM3(acc3, xh, xl, bh, bl);
      FRAGS(6, xh, xl, bh, bl, i2h, i2l);  MM3(acc2, xh, xl, bh, bl);
      FRAGS(7, xh, xl, bh, bl, i2h, i2l);  MM3(acc3, xh, xl, bh, bl);
    }

    // ---- epilogue: scale + recenter + store ----
    #pragma unroll
    for (int g = 0; g < 16; ++g) {
      const int rq = (g & 3) + 8*(g >> 2) + 4*ah;
      float o = fmaf(acc2[g] + acc3[g], norms[rq], meanv);
      out[(size_t)(chb + rq)*128 + w*32 + al] = o;
    }
    __syncthreads();              // mm2 reads done before next stage
  }
}

// =======================================================================
// K_fix: exact f64 recompute of rows with any element within MARGIN of
// a quantization midpoint. One wave per row; overwrites out.
// =======================================================================
__global__ __launch_bounds__(256)
void kfix(const float* __restrict__ x, const float* __restrict__ mean,
          const float* __restrict__ cent, const double* __restrict__ Rt64,
          float* __restrict__ out,
          const unsigned int* __restrict__ counter,
          const unsigned int* __restrict__ list)
{
  __shared__ double xs[4][128];
  __shared__ double qs[4][128];
  const int tid = threadIdx.x, lane = tid & 63, w = tid >> 6;

  unsigned cnt = *counter;
  if (cnt > LIST_CAP) cnt = LIST_CAP;

  const double cc0 = (double)cent[0], cc1 = (double)cent[1], cc2 = (double)cent[2],
               cc3 = (double)cent[3], cc4 = (double)cent[4], cc5 = (double)cent[5],
               cc6 = (double)cent[6], cc7 = (double)cent[7];
  const double m0 = 0.5*(cc0+cc1), m1 = 0.5*(cc1+cc2), m2 = 0.5*(cc2+cc3),
               m3 = 0.5*(cc3+cc4), m4 = 0.5*(cc4+cc5), m5 = 0.5*(cc5+cc6),
               m6 = 0.5*(cc6+cc7);

  const unsigned gw = blockIdx.x*4 + w, stride = gridDim.x*4;
  for (unsigned e = gw; e < cnt; e += stride) {
    const int row = (int)list[e];
    const float* xr = x + (size_t)row*128;
    const int j0 = 2*lane;

    double a = (double)xr[j0]   - (double)mean[j0];
    double b = (double)xr[j0+1] - (double)mean[j0+1];
    double s = a*a + b*b;
    s += __shfl_xor(s, 1);  s += __shfl_xor(s, 2);  s += __shfl_xor(s, 4);
    s += __shfl_xor(s, 8);  s += __shfl_xor(s, 16); s += __shfl_xor(s, 32);
    double n = sqrt(s);
    if (n < 1e-8) n = 1e-8;
    double inv = 1.0 / n;
    xs[w][j0]   = a * inv;
    xs[w][j0+1] = b * inv;
    asm volatile("s_waitcnt lgkmcnt(0)" ::: "memory");

    double acc0 = 0.0, acc1 = 0.0;
    for (int j = 0; j < 128; ++j) {
      double xj = xs[w][j];
      acc0 = fma(xj, Rt64[j*128 + j0],     acc0);
      acc1 = fma(xj, Rt64[j*128 + j0 + 1], acc1);
    }
    double q0 = cc0;
    q0 = (acc0 > m0) ? cc1 : q0;  q0 = (acc0 > m1) ? cc2 : q0;
    q0 = (acc0 > m2) ? cc3 : q0;  q0 = (acc0 > m3) ? cc4 : q0;
    q0 = (acc0 > m4) ? cc5 : q0;  q0 = (acc0 > m5) ? cc6 : q0;
    q0 = (acc0 > m6) ? cc7 : q0;
    double q1 = cc0;
    q1 = (acc1 > m0) ? cc1 : q1;  q1 = (acc1 > m1) ? cc2 : q1;
    q1 = (acc1 > m2) ? cc3 : q1;  q1 = (acc1 > m3) ? cc4 : q1;
    q1 = (acc1 > m4) ? cc5 : q1;  q1 = (acc1 > m5) ? cc6 : q1;
    q1 = (acc1 > m6) ? cc7 : q1;
    qs[w][j0]   = q0;
    qs[w][j0+1] = q1;
    asm volatile("s_waitcnt lgkmcnt(0)" ::: "memory");

    double o0 = 0.0, o1 = 0.0;
    for (int k = 0; k < 128; ++k) {
      double qk = qs[w][k];
      o0 = fma(qk, Rt64[j0*128 + k],       o0);
      o1 = fma(qk, Rt64[(j0+1)*128 + k],   o1);
    }
    out[(size_t)row*128 + j0]   = (float)fma(o0, n, (double)mean[j0]);
    out[(size_t)row*128 + j0+1] = (float)fma(o1, n, (double)mean[j0+1]);
  }
}

// =======================================================================
extern "C" void kernel_launch(void* const* d_in, const int* in_sizes, int n_in,
                              void* d_out, int out_size, void* d_ws, size_t ws_size,
                              hipStream_t stream)
{
  (void)in_sizes; (void)n_in; (void)out_size; (void)ws_size;
  const float* x    = (const float*)d_in[0];
  const float* skew = (const float*)d_in[1];
  const float* cent = (const float*)d_in[2];
  const float* mean = (const float*)d_in[3];
  float* out = (float*)d_out;

  char* ws = (char*)d_ws;
  double*         Rt64 = (double*)(ws);
  unsigned short* img  = (unsigned short*)(ws + 131072);
  unsigned int*   cntr = (unsigned int*)(ws + 262144);
  unsigned int*   list = (unsigned int*)(ws + 262912);

  hipMemsetAsync(cntr, 0, 4, stream);
  kpre <<<dim3(1),    dim3(1024), 0, stream>>>(skew, Rt64, img);
  kmain<<<dim3(1024), dim3(256),  0, stream>>>(x, mean, cent, img, out, cntr, list);
  kfix <<<dim3(192),  dim3(256),  0, stream>>>(x, mean, cent, Rt64, out, cntr, list);
}

// Round 5
// 303.127 us; speedup vs baseline: 2.3592x; 1.9104x over previous
//
#include <hip/hip_runtime.h>

#define BATCH 262144
#define MARGIN 1e-5f
#define LIST_CAP (1u<<20)

typedef __attribute__((ext_vector_type(8))) short short8;
typedef __attribute__((ext_vector_type(16))) float f32x16;

// ---------------- workspace layout (bytes) ----------------
// 0       : Rt64 f64[128][128]  Rt64[j*128+k] = R[k][j]      (131072)
// 131072  : img  u16: i1h[16384] i1l[16384] i2h[16384] i2l[16384] (131072)
//           img1 frag(kb,jc): lane l,e -> R[kb*32+(l&31)][jc*16+8*(l>>5)+e]  (mm1 B)
//           img2 frag(jb,kc): lane l,e -> R[kc*16+8*(l>>5)+e][jb*32+(l&31)]  (mm2 B)
// 262144  : counter u32
// 262912  : list u32[LIST_CAP]  (row ids, dups ok)

__device__ __forceinline__ unsigned f2bf(float f) {
  unsigned u = __float_as_uint(f);
  return (u + 0x7FFFu + ((u >> 16) & 1u)) >> 16;   // RTN-even bf16
}
__device__ __forceinline__ unsigned packsplit(float f) {
  unsigned h = f2bf(f);
  float hf = __uint_as_float(h << 16);
  unsigned l = f2bf(f - hf);
  return (h << 16) | l;
}

// =======================================================================
// K_pre: register-resident Gauss-Jordan inversion of M = I + A (no
// pivoting; cond ~1.5). 2 barriers/iter: next pivot column published
// during elimination (ping-pong colk). R = 2*(I+A)^-1 - I.
// =======================================================================
__global__ __launch_bounds__(1024)
void kpre(const float* __restrict__ skew, double* __restrict__ Rt64,
          unsigned short* __restrict__ img)
{
  __shared__ double colk[2][128];
  __shared__ double pivrow[128];
  const int tid = threadIdx.x;
  const int i = tid >> 3;
  const int s = tid & 7;

  double M[16];
  #pragma unroll
  for (int e = 0; e < 16; ++e) {
    int j = s + 8*e;
    double v;
    if (i == j)      v = 1.0;
    else if (i < j)  v =  (double)skew[i*127 - (i*(i-1))/2 + (j - i - 1)];
    else             v = -(double)skew[j*127 - (j*(j-1))/2 + (i - j - 1)];
    M[e] = v;
  }
  if (s == 0) colk[0][i] = M[0];   // publish column 0
  __syncthreads();

  for (int k = 0; k < 128; ++k) {
    const int p = k & 1, np = p ^ 1, ns = (k + 1) & 7, ne = (k + 1) >> 3;
    if (i == k) {
      double rec = 1.0 / colk[p][k];
      #pragma unroll
      for (int e = 0; e < 16; ++e) {
        int j = s + 8*e;
        double v = (j == k) ? 1.0 : M[e];
        v *= rec;
        M[e] = v;
        pivrow[j] = v;
      }
      if (s == ns) colk[np][i] = M[ne];
    }
    __syncthreads();
    if (i != k) {
      double f = colk[p][i];
      #pragma unroll
      for (int e = 0; e < 16; ++e) {
        int j = s + 8*e;
        double v = (j == k) ? 0.0 : M[e];
        M[e] = fma(-f, pivrow[j], v);
      }
      if (s == ns) colk[np][i] = M[ne];
    }
    __syncthreads();
  }

  #pragma unroll
  for (int e = 0; e < 16; ++e) {
    int j = s + 8*e;
    double v = 2.0 * M[e] - ((i == j) ? 1.0 : 0.0);    // R[i][j]
    Rt64[j*128 + i] = v;
    float r32 = (float)v;
    unsigned h = f2bf(r32);
    unsigned l = f2bf(r32 - __uint_as_float(h << 16));
    int off1 = (((i>>5)*8 + (j>>4))*64 + ((((j>>3)&1)<<5) | (i&31)))*8 + (j&7);
    img[off1]          = (unsigned short)h;
    img[16384 + off1]  = (unsigned short)l;
    int off2 = (((j>>5)*8 + (i>>4))*64 + ((((i>>3)&1)<<5) | (j&31)))*8 + (i&7);
    img[32768 + off2]  = (unsigned short)h;
    img[49152 + off2]  = (unsigned short)l;
  }
}

// =======================================================================
// K_main: fused rotate+quantize+reconstruct. 1024 blocks x 256 thr.
// B-fragments (the wave's w-slice of both R images) live in REGISTERS
// for the whole kernel (128 VGPRs, zero inner-loop global B traffic).
// X and Q hi/lo LDS images are double-buffered -> 2 barriers/chunk.
// x prefetched one chunk ahead into registers.
// =======================================================================
#define MM3(ACC, XH, XL, BH, BL)                                        \
  ACC = __builtin_amdgcn_mfma_f32_32x32x16_bf16(XH, BH, ACC, 0, 0, 0);  \
  ACC = __builtin_amdgcn_mfma_f32_32x32x16_bf16(XL, BH, ACC, 0, 0, 0);  \
  ACC = __builtin_amdgcn_mfma_f32_32x32x16_bf16(XH, BL, ACC, 0, 0, 0);

__global__ __launch_bounds__(256, 2)
void kmain(const float* __restrict__ x, const float* __restrict__ mean,
           const float* __restrict__ cent, const unsigned short* __restrict__ img,
           float* __restrict__ out,
           unsigned int* __restrict__ counter, unsigned int* __restrict__ list)
{
  __shared__ __align__(16) unsigned short Xh[2][32*128];   // 2 x 8 KB (swizzled)
  __shared__ __align__(16) unsigned short Xl[2][32*128];
  __shared__ __align__(16) unsigned short Qh[2][32*128];
  __shared__ __align__(16) unsigned short Ql[2][32*128];
  __shared__ float norms[2][32];
  __shared__ float invs[2][32];

  const int tid = threadIdx.x, lane = tid & 63, w = tid >> 6;
  const int al = lane & 31, ah = lane >> 5;

  // ---- loop-invariant B fragments -> registers (128 VGPRs) ----
  short8 B1h[8], B1l[8], B2h[8], B2l[8];
  #pragma unroll
  for (int t = 0; t < 8; ++t) {
    size_t o = (size_t)((w*8 + t)*64 + lane)*8;
    B1h[t] = *(const short8*)(img +         o);
    B1l[t] = *(const short8*)(img + 16384 + o);
    B2h[t] = *(const short8*)(img + 32768 + o);
    B2l[t] = *(const short8*)(img + 49152 + o);
  }

  const float c0 = cent[0], c1 = cent[1], c2 = cent[2], c3 = cent[3];
  const float c4 = cent[4], c5 = cent[5], c6 = cent[6], c7 = cent[7];
  const float mid0 = 0.5f*(c0+c1), mid1 = 0.5f*(c1+c2), mid2 = 0.5f*(c2+c3),
              mid3 = 0.5f*(c3+c4), mid4 = 0.5f*(c4+c5), mid5 = 0.5f*(c5+c6),
              mid6 = 0.5f*(c6+c7);
  const unsigned qt0 = packsplit(c0), qt1 = packsplit(c1), qt2 = packsplit(c2),
                 qt3 = packsplit(c3), qt4 = packsplit(c4), qt5 = packsplit(c5),
                 qt6 = packsplit(c6), qt7 = packsplit(c7);

  const float2 mean2 = *(const float2*)(mean + 2*lane);
  const float meanv = mean[w*32 + al];

  const int row0 = blockIdx.x * 256;

  // prefetch chunk 0
  float2 xpf[8];
  #pragma unroll
  for (int rr = 0; rr < 8; ++rr)
    xpf[rr] = *(const float2*)(x + (size_t)(row0 + w*8 + rr)*128 + 2*lane);

  for (int ch = 0; ch < 8; ++ch) {
    const int chb = row0 + ch*32;
    const int p = ch & 1;

    // ---- Phase A: issue next-chunk loads; pack current -> X[p] ----
    float2 xn[8];
    if (ch < 7) {
      #pragma unroll
      for (int rr = 0; rr < 8; ++rr)
        xn[rr] = *(const float2*)(x + (size_t)(chb + 32 + w*8 + rr)*128 + 2*lane);
    }
    #pragma unroll
    for (int rr = 0; rr < 8; ++rr) {
      const int r = w*8 + rr;
      float a = xpf[rr].x - mean2.x;
      float b = xpf[rr].y - mean2.y;
      float sq = fmaf(a, a, b*b);
      sq += __shfl_xor(sq, 1);  sq += __shfl_xor(sq, 2);  sq += __shfl_xor(sq, 4);
      sq += __shfl_xor(sq, 8);  sq += __shfl_xor(sq, 16); sq += __shfl_xor(sq, 32);
      unsigned pa = packsplit(a), pb = packsplit(b);
      unsigned off = ((unsigned)(r*256 + 4*lane)) ^ (((unsigned)(r & 7)) << 4);
      *(unsigned*)((char*)&Xh[p][0] + off) = (pb & 0xFFFF0000u) | (pa >> 16);
      *(unsigned*)((char*)&Xl[p][0] + off) = (pb << 16) | (pa & 0xFFFFu);
      if (lane == 0) {
        float n = fmaxf(sqrtf(sq), 1e-8f);
        norms[p][r] = n;
        invs[p][r]  = 1.0f / n;
      }
    }
    #pragma unroll
    for (int rr = 0; rr < 8; ++rr) xpf[rr] = xn[rr];
    __syncthreads();                                  // bar1: X[p] ready

    // ---- Phase B: mm1 (X[p] x B1 regs), quantize, write Q[p] ----
    f32x16 accA, accB;
    #pragma unroll
    for (int g = 0; g < 16; ++g) { accA[g] = 0.0f; accB[g] = 0.0f; }
    __builtin_amdgcn_s_setprio(1);
    #pragma unroll
    for (int t = 0; t < 8; ++t) {
      unsigned fb = ((unsigned)(al*256 + t*32 + ah*16)) ^ (((unsigned)(al & 7)) << 4);
      short8 xh = *(const short8*)((const char*)&Xh[p][0] + fb);
      short8 xl = *(const short8*)((const char*)&Xl[p][0] + fb);
      if (t & 1) { MM3(accB, xh, xl, B1h[t], B1l[t]); }
      else       { MM3(accA, xh, xl, B1h[t], B1l[t]); }
    }
    __builtin_amdgcn_s_setprio(0);
    #pragma unroll
    for (int g = 0; g < 16; ++g) accA[g] += accB[g];

    unsigned qp[16];
    unsigned flags = 0;
    #pragma unroll
    for (int g = 0; g < 16; ++g) {
      const int r = (g & 3) + 8*(g >> 2) + 4*ah;
      float xr = accA[g] * invs[p][r];
      unsigned q = qt0;
      q = (xr > mid0) ? qt1 : q;  q = (xr > mid1) ? qt2 : q;
      q = (xr > mid2) ? qt3 : q;  q = (xr > mid3) ? qt4 : q;
      q = (xr > mid4) ? qt5 : q;  q = (xr > mid5) ? qt6 : q;
      q = (xr > mid6) ? qt7 : q;
      float dm = fabsf(xr - mid0);
      dm = fminf(dm, fabsf(xr - mid1)); dm = fminf(dm, fabsf(xr - mid2));
      dm = fminf(dm, fabsf(xr - mid3)); dm = fminf(dm, fabsf(xr - mid4));
      dm = fminf(dm, fabsf(xr - mid5)); dm = fminf(dm, fabsf(xr - mid6));
      qp[g] = q;
      flags |= (dm < MARGIN) ? (1u << g) : 0u;
    }
    #pragma unroll
    for (int g = 0; g < 16; ++g) {
      const int rq = (g & 3) + 8*(g >> 2) + 4*ah;
      unsigned off = ((unsigned)(rq*256 + (w*32 + al)*2)) ^ (((unsigned)(rq & 7)) << 4);
      *(unsigned short*)((char*)&Qh[p][0] + off) = (unsigned short)(qp[g] >> 16);
      *(unsigned short*)((char*)&Ql[p][0] + off) = (unsigned short)(qp[g] & 0xFFFFu);
    }
    if (__builtin_amdgcn_ballot_w64(flags != 0)) {   // rare path
      #pragma unroll
      for (int g = 0; g < 16; ++g) {
        unsigned long long b = __ballot((flags >> g) & 1u);
        if (b) {
          const int rq = (g & 3) + 8*(g >> 2) + 4*ah;
          unsigned base = 0;
          if (lane == 0) base = atomicAdd(counter, (unsigned)__popcll(b));
          base = (unsigned)__shfl((int)base, 0);
          if ((flags >> g) & 1u) {
            unsigned pp = base + (unsigned)__popcll(b & ((1ull << lane) - 1ull));
            if (pp < LIST_CAP) list[pp] = (unsigned)(chb + rq);
          }
        }
      }
    }
    __syncthreads();                                  // bar2: Q[p] ready

    // ---- Phase C: mm2 (Q[p] x B2 regs), scale + store ----
    f32x16 acc2, acc3;
    #pragma unroll
    for (int g = 0; g < 16; ++g) { acc2[g] = 0.0f; acc3[g] = 0.0f; }
    __builtin_amdgcn_s_setprio(1);
    #pragma unroll
    for (int t = 0; t < 8; ++t) {
      unsigned fb = ((unsigned)(al*256 + t*32 + ah*16)) ^ (((unsigned)(al & 7)) << 4);
      short8 xh = *(const short8*)((const char*)&Qh[p][0] + fb);
      short8 xl = *(const short8*)((const char*)&Ql[p][0] + fb);
      if (t & 1) { MM3(acc3, xh, xl, B2h[t], B2l[t]); }
      else       { MM3(acc2, xh, xl, B2h[t], B2l[t]); }
    }
    __builtin_amdgcn_s_setprio(0);

    #pragma unroll
    for (int g = 0; g < 16; ++g) {
      const int rq = (g & 3) + 8*(g >> 2) + 4*ah;
      float o = fmaf(acc2[g] + acc3[g], norms[p][rq], meanv);
      out[(size_t)(chb + rq)*128 + w*32 + al] = o;
    }
  }
}

// =======================================================================
// K_fix: exact f64 recompute of rows with any element within MARGIN of
// a quantization midpoint. One wave per row; overwrites out.
// =======================================================================
__global__ __launch_bounds__(256)
void kfix(const float* __restrict__ x, const float* __restrict__ mean,
          const float* __restrict__ cent, const double* __restrict__ Rt64,
          float* __restrict__ out,
          const unsigned int* __restrict__ counter,
          const unsigned int* __restrict__ list)
{
  __shared__ double xs[4][128];
  __shared__ double qs[4][128];
  const int tid = threadIdx.x, lane = tid & 63, w = tid >> 6;

  unsigned cnt = *counter;
  if (cnt > LIST_CAP) cnt = LIST_CAP;

  const double cc0 = (double)cent[0], cc1 = (double)cent[1], cc2 = (double)cent[2],
               cc3 = (double)cent[3], cc4 = (double)cent[4], cc5 = (double)cent[5],
               cc6 = (double)cent[6], cc7 = (double)cent[7];
  const double m0 = 0.5*(cc0+cc1), m1 = 0.5*(cc1+cc2), m2 = 0.5*(cc2+cc3),
               m3 = 0.5*(cc3+cc4), m4 = 0.5*(cc4+cc5), m5 = 0.5*(cc5+cc6),
               m6 = 0.5*(cc6+cc7);

  const unsigned gw = blockIdx.x*4 + w, stride = gridDim.x*4;
  for (unsigned e = gw; e < cnt; e += stride) {
    const int row = (int)list[e];
    const float* xr = x + (size_t)row*128;
    const int j0 = 2*lane;

    double a = (double)xr[j0]   - (double)mean[j0];
    double b = (double)xr[j0+1] - (double)mean[j0+1];
    double s = a*a + b*b;
    s += __shfl_xor(s, 1);  s += __shfl_xor(s, 2);  s += __shfl_xor(s, 4);
    s += __shfl_xor(s, 8);  s += __shfl_xor(s, 16); s += __shfl_xor(s, 32);
    double n = sqrt(s);
    if (n < 1e-8) n = 1e-8;
    double inv = 1.0 / n;
    xs[w][j0]   = a * inv;
    xs[w][j0+1] = b * inv;
    asm volatile("s_waitcnt lgkmcnt(0)" ::: "memory");

    double acc0 = 0.0, acc1 = 0.0;
    for (int j = 0; j < 128; ++j) {
      double xj = xs[w][j];
      acc0 = fma(xj, Rt64[j*128 + j0],     acc0);
      acc1 = fma(xj, Rt64[j*128 + j0 + 1], acc1);
    }
    double q0 = cc0;
    q0 = (acc0 > m0) ? cc1 : q0;  q0 = (acc0 > m1) ? cc2 : q0;
    q0 = (acc0 > m2) ? cc3 : q0;  q0 = (acc0 > m3) ? cc4 : q0;
    q0 = (acc0 > m4) ? cc5 : q0;  q0 = (acc0 > m5) ? cc6 : q0;
    q0 = (acc0 > m6) ? cc7 : q0;
    double q1 = cc0;
    q1 = (acc1 > m0) ? cc1 : q1;  q1 = (acc1 > m1) ? cc2 : q1;
    q1 = (acc1 > m2) ? cc3 : q1;  q1 = (acc1 > m3) ? cc4 : q1;
    q1 = (acc1 > m4) ? cc5 : q1;  q1 = (acc1 > m5) ? cc6 : q1;
    q1 = (acc1 > m6) ? cc7 : q1;
    qs[w][j0]   = q0;
    qs[w][j0+1] = q1;
    asm volatile("s_waitcnt lgkmcnt(0)" ::: "memory");

    double o0 = 0.0, o1 = 0.0;
    for (int k = 0; k < 128; ++k) {
      double qk = qs[w][k];
      o0 = fma(qk, Rt64[j0*128 + k],       o0);
      o1 = fma(qk, Rt64[(j0+1)*128 + k],   o1);
    }
    out[(size_t)row*128 + j0]   = (float)fma(o0, n, (double)mean[j0]);
    out[(size_t)row*128 + j0+1] = (float)fma(o1, n, (double)mean[j0+1]);
  }
}

// =======================================================================
extern "C" void kernel_launch(void* const* d_in, const int* in_sizes, int n_in,
                              void* d_out, int out_size, void* d_ws, size_t ws_size,
                              hipStream_t stream)
{
  (void)in_sizes; (void)n_in; (void)out_size; (void)ws_size;
  const float* x    = (const float*)d_in[0];
  const float* skew = (const float*)d_in[1];
  const float* cent = (const float*)d_in[2];
  const float* mean = (const float*)d_in[3];
  float* out = (float*)d_out;

  char* ws = (char*)d_ws;
  double*         Rt64 = (double*)(ws);
  unsigned short* img  = (unsigned short*)(ws + 131072);
  unsigned int*   cntr = (unsigned int*)(ws + 262144);
  unsigned int*   list = (unsigned int*)(ws + 262912);

  hipMemsetAsync(cntr, 0, 4, stream);
  kpre <<<dim3(1),    dim3(1024), 0, stream>>>(skew, Rt64, img);
  kmain<<<dim3(1024), dim3(256),  0, stream>>>(x, mean, cent, img, out, cntr, list);
  kfix <<<dim3(256),  dim3(256),  0, stream>>>(x, mean, cent, Rt64, out, cntr, list);
}